// Round 1
// baseline (76.710 us; speedup 1.0000x reference)
//
#include <hip/hip_runtime.h>

#define H_ 64
#define W_ 64
#define NCV 8   // n_convs
#define KK 9
#define NCOEF 8

// One thread per (b*c, ho, wo). Each thread computes all 8 conv outputs.
__global__ __launch_bounds__(256) void kan_conv_kernel(
    const float* __restrict__ x,     // (256, 64, 64)
    const float* __restrict__ bw,    // (8, 9)
    const float* __restrict__ sw,    // (8, 9, 8)
    const float* __restrict__ ss,    // (8, 9)
    float* __restrict__ out)         // (16, 128, 64, 64)
{
    // LDS weights: [i][f][n], f=0 -> base weight, f=1+g -> spline weight * scaler
    // inner dim padded 8->12 floats (48B row stride) to spread banks on the gather
    __shared__ float Wl[9][9][12];

    const int tid = threadIdx.y * 64 + threadIdx.x;
    for (int idx = tid; idx < 9 * 9 * 8; idx += 256) {
        int i   = idx / 72;
        int rem = idx - i * 72;
        int f   = rem >> 3;
        int n   = rem & 7;
        float w;
        if (f == 0) w = bw[n * KK + i];
        else        w = sw[(n * KK + i) * NCOEF + (f - 1)] * ss[n * KK + i];
        Wl[i][f][n] = w;
    }
    __syncthreads();

    const int wo = threadIdx.x;               // 0..63
    const int ho = blockIdx.x * 4 + threadIdx.y; // 0..63
    const int bc = blockIdx.y;                // 0..255  (= b*16 + c)
    const float* __restrict__ xin = x + (size_t)bc * (H_ * W_);

    float acc[8] = {0.f, 0.f, 0.f, 0.f, 0.f, 0.f, 0.f, 0.f};

    const float c6 = 1.f / 6.f;

    #pragma unroll
    for (int i = 0; i < 9; ++i) {
        const int di = i / 3 - 1;
        const int dj = i % 3 - 1;
        const int yy = ho + di;
        const int xx = wo + dj;
        const bool inb = (yy >= 0) & (yy < H_) & (xx >= 0) & (xx < W_);
        const float v = inb ? xin[yy * W_ + xx] : 0.f;

        // silu
        const float s = v / (1.f + __expf(-v));

        // uniform cubic B-spline: span index + local coordinate
        const float u  = (v + 2.2f) * 2.5f;    // (v - grid[0]) / h
        const float mf = floorf(u);
        const float t  = u - mf;
        const int   m  = (int)mf;
        const float t2 = t * t, t3 = t2 * t;
        const float omt = 1.f - t;
        float wr0 = c6 * omt * omt * omt;                      // N_{m-3}
        float wr1 = c6 * (3.f * t3 - 6.f * t2 + 4.f);          // N_{m-2}
        float wr2 = c6 * (-3.f * t3 + 3.f * t2 + 3.f * t + 1.f); // N_{m-1}
        float wr3 = c6 * t3;                                   // N_m
        const bool valid = (m >= 0) & (m <= 10);

        // base contribution (uniform LDS address -> broadcast)
        {
            const float4* bp = (const float4*)&Wl[i][0][0];
            const float4 ba = bp[0], bb = bp[1];
            acc[0] += s * ba.x; acc[1] += s * ba.y; acc[2] += s * ba.z; acc[3] += s * ba.w;
            acc[4] += s * bb.x; acc[5] += s * bb.y; acc[6] += s * bb.z; acc[7] += s * bb.w;
        }

        // spline contribution: only 4 bases nonzero, gather their weight rows
        float wrv[4] = {wr0, wr1, wr2, wr3};
        #pragma unroll
        for (int r = 0; r < 4; ++r) {
            const int g = m - 3 + r;
            const bool ok = valid & (g >= 0) & (g < 8);
            const float we = ok ? wrv[r] : 0.f;
            const int gc = min(max(g, 0), 7);
            const float4* wp = (const float4*)&Wl[i][1 + gc][0];
            const float4 wa = wp[0], wb = wp[1];
            acc[0] += we * wa.x; acc[1] += we * wa.y; acc[2] += we * wa.z; acc[3] += we * wa.w;
            acc[4] += we * wb.x; acc[5] += we * wb.y; acc[6] += we * wb.z; acc[7] += we * wb.w;
        }
    }

    float* __restrict__ op = out + (size_t)bc * (NCV * H_ * W_) + ho * W_ + wo;
    #pragma unroll
    for (int n = 0; n < 8; ++n) op[n * (H_ * W_)] = acc[n];
}

extern "C" void kernel_launch(void* const* d_in, const int* in_sizes, int n_in,
                              void* d_out, int out_size, void* d_ws, size_t ws_size,
                              hipStream_t stream) {
    const float* x  = (const float*)d_in[0];
    const float* bw = (const float*)d_in[1];
    const float* sw = (const float*)d_in[2];
    const float* ss = (const float*)d_in[3];
    float* out = (float*)d_out;

    dim3 block(64, 4, 1);
    dim3 grid(16, 256, 1);   // (Ho/4, B*C)
    hipLaunchKernelGGL(kan_conv_kernel, grid, block, 0, stream, x, bw, sw, ss, out);
}

// Round 2
// 28.278 us; speedup vs baseline: 2.7127x; 2.7127x over previous
//
#include <hip/hip_runtime.h>

typedef _Float16 half8 __attribute__((ext_vector_type(8)));

#define Hh 64
#define Ww 64

// Wave = one 4-row x 64-col output strip of one (b,c) plane. Lane = column.
// LDS weights fp16: Wl[i][row][n]; rows 0..13 = spline g+3 (zero-padded ends),
// row 14 = base weight. Tap read = 4 contiguous b128 (rows m..m+3) + base row.
__global__ __launch_bounds__(256, 4) void kan_conv_kernel(
    const float* __restrict__ x,     // (256, 64, 64)
    const float* __restrict__ bw,    // (8, 9)
    const float* __restrict__ sw,    // (8, 9, 8)
    const float* __restrict__ ss,    // (8, 9)
    float* __restrict__ out)         // (256, 8, 64, 64)
{
    __shared__ __align__(16) _Float16 Wl[9][15][8];

    const int tid = threadIdx.x;
    for (int idx = tid; idx < 9 * 15 * 8; idx += 256) {
        int i   = idx / 120;
        int rem = idx - i * 120;
        int gg  = rem >> 3;
        int n   = rem & 7;
        float w = 0.f;
        if (gg == 14)               w = bw[n * 9 + i];
        else if (gg >= 3 && gg <= 10) w = sw[(n * 9 + i) * 8 + (gg - 3)] * ss[n * 9 + i];
        Wl[i][gg][n] = (_Float16)w;
    }
    __syncthreads();

    const int lane = tid & 63;
    const int wv   = tid >> 6;            // wave in block: 0..3
    const int bc   = blockIdx.x >> 2;     // 0..255
    const int grp  = blockIdx.x & 3;      // 0..3
    const int r0   = grp * 16 + wv * 4;   // strip start output row

    const float* __restrict__ xin = x + (size_t)bc * (Hh * Ww);
    float* __restrict__ op = out + (size_t)bc * (8 * Hh * Ww) + (size_t)r0 * Ww + lane;

    // rolling feature sets: [set][col]  col: 0=left,1=center,2=right
    float Fs[3][3];       // silu value
    float Fw[3][3][4];    // 4 spline basis weights
    int   Fm[3][3];       // span row index m (clamped)

    auto loadrow = [&](int y, int set) {
        float vC = 0.f, vL = 0.f, vR = 0.f;
        if ((unsigned)y < (unsigned)Hh) {
            const float* row = xin + y * Ww;
            vC = row[lane];
            vL = (lane == 0)  ? 0.f : row[lane - 1];
            vR = (lane == 63) ? 0.f : row[lane + 1];
        }
        float vv[3] = {vL, vC, vR};
        #pragma unroll
        for (int c = 0; c < 3; ++c) {
            float v = vv[c];
            float s = __fdividef(v, 1.f + __expf(-v));          // silu
            float u  = (v + 2.2f) * 2.5f;
            float mf = floorf(u);
            float t  = u - mf;
            int   m  = (int)mf;
            bool  inr = (m >= 0) && (m <= 10);
            m = min(max(m, 0), 10);
            float t2 = t * t, t3 = t2 * t, omt = 1.f - t;
            const float c6 = 1.f / 6.f;
            float w0 = c6 * omt * omt * omt;
            float w1 = c6 * (3.f * t3 - 6.f * t2 + 4.f);
            float w2 = c6 * (-3.f * t3 + 3.f * t2 + 3.f * t + 1.f);
            float w3 = c6 * t3;
            if (!inr) { w0 = 0.f; w1 = 0.f; w2 = 0.f; w3 = 0.f; }
            Fs[set][c] = s;
            Fw[set][c][0] = w0; Fw[set][c][1] = w1;
            Fw[set][c][2] = w2; Fw[set][c][3] = w3;
            Fm[set][c] = m;
        }
    };

    loadrow(r0 - 1, 0);
    loadrow(r0,     1);

    #pragma unroll
    for (int rr = 0; rr < 4; ++rr) {
        loadrow(r0 + rr + 1, (rr + 2) % 3);

        float acc[8];
        #pragma unroll
        for (int n = 0; n < 8; ++n) acc[n] = 0.f;

        #pragma unroll
        for (int ir = 0; ir < 3; ++ir) {          // tap row (di+1)
            const int set = (rr + ir) % 3;
            #pragma unroll
            for (int c = 0; c < 3; ++c) {         // tap col (dj+1)
                const int i = ir * 3 + c;
                const half8* blk = (const half8*)&Wl[i][0][0];
                const half8* rp  = blk + Fm[set][c];
                half8 h0 = rp[0], h1 = rp[1], h2 = rp[2], h3 = rp[3];
                half8 hb = blk[14];
                const float w0 = Fw[set][c][0], w1 = Fw[set][c][1];
                const float w2 = Fw[set][c][2], w3 = Fw[set][c][3];
                const float s  = Fs[set][c];
                #pragma unroll
                for (int n = 0; n < 8; ++n) {
                    float a = acc[n];
                    a += w0 * (float)h0[n];
                    a += w1 * (float)h1[n];
                    a += w2 * (float)h2[n];
                    a += w3 * (float)h3[n];
                    a += s  * (float)hb[n];
                    acc[n] = a;
                }
            }
        }

        #pragma unroll
        for (int n = 0; n < 8; ++n)
            op[n * (Hh * Ww) + rr * Ww] = acc[n];
    }
}

extern "C" void kernel_launch(void* const* d_in, const int* in_sizes, int n_in,
                              void* d_out, int out_size, void* d_ws, size_t ws_size,
                              hipStream_t stream) {
    const float* x  = (const float*)d_in[0];
    const float* bw = (const float*)d_in[1];
    const float* sw = (const float*)d_in[2];
    const float* ss = (const float*)d_in[3];
    float* out = (float*)d_out;

    dim3 block(256, 1, 1);
    dim3 grid(1024, 1, 1);   // 256 bc * 4 strip-groups; wave = 4-row strip
    hipLaunchKernelGGL(kan_conv_kernel, grid, block, 0, stream, x, bw, sw, ss, out);
}

// Round 4
// 25.207 us; speedup vs baseline: 3.0431x; 1.1218x over previous
//
#include <hip/hip_runtime.h>

typedef __fp16 h2 __attribute__((ext_vector_type(2)));

#define Hh 64
#define Ww 64

__device__ __forceinline__ h2 f2h2(float f) { return __builtin_bit_cast(h2, f); }

// Wave = one 4-row x 64-col output strip of one (b,c) plane. Lane = column.
// LDS spline table as PAIR-ROWS: Pl[i][g][n] = (Wrow[g][n], Wrow[g+1][n]) f16,
// where Wrow[r] = spline coef (r-3) scaled; rows 0..2 and 11..13 are zero.
// A tap reads pair-rows m and m+2 (4 ds_read_b128) and does 2 fdot2 per n.
// Base (silu) weights are pixel-invariant -> hoisted to registers, fdot2-paired.
__global__ __launch_bounds__(256, 4) void kan_conv_kernel(
    const float* __restrict__ x,     // (256, 64, 64)
    const float* __restrict__ bw,    // (8, 9)
    const float* __restrict__ sw,    // (8, 9, 8)
    const float* __restrict__ ss,    // (8, 9)
    float* __restrict__ out)         // (256, 8, 64, 64)
{
    __shared__ __align__(16) h2 Pl[9][14][8];

    const int tid = threadIdx.x;
    for (int idx = tid; idx < 9 * 14 * 8; idx += 256) {
        int i   = idx / 112;
        int rem = idx - i * 112;
        int g   = rem >> 3;
        int n   = rem & 7;
        const float sc = ss[n * 9 + i];
        float w0 = 0.f, w1 = 0.f;
        if (g >= 3 && g <= 10)         w0 = sw[(n * 9 + i) * 8 + (g - 3)] * sc;
        if (g + 1 >= 3 && g + 1 <= 10) w1 = sw[(n * 9 + i) * 8 + (g - 2)] * sc;
        h2 p; p.x = (__fp16)w0; p.y = (__fp16)w1;
        Pl[i][g][n] = p;
    }
    __syncthreads();

    const int lane = tid & 63;
    const int wv   = tid >> 6;            // wave in block: 0..3
    const int bc   = blockIdx.x >> 2;     // 0..255
    const int grp  = blockIdx.x & 3;      // 0..3
    const int r0   = grp * 16 + wv * 4;   // strip start output row

    const float* __restrict__ xin = x + (size_t)bc * (Hh * Ww);
    float* __restrict__ op = out + (size_t)bc * (8 * Hh * Ww) + (size_t)r0 * Ww + lane;

    // Base weights hoisted: pairs (i=2p, 2p+1) as f16x2, plus single i=8 (f32).
    h2    hbp[4][8];
    float hb8[8];
    #pragma unroll
    for (int n = 0; n < 8; ++n) {
        #pragma unroll
        for (int p = 0; p < 4; ++p) {
            h2 h;
            h.x = (__fp16)bw[n * 9 + 2 * p];
            h.y = (__fp16)bw[n * 9 + 2 * p + 1];
            hbp[p][n] = h;
        }
        hb8[n] = bw[n * 9 + 8];
    }

    // rolling feature sets: [set][col]  col: 0=left,1=center,2=right
    float Fs[3][3];      // silu value (f32)
    h2    Fw01[3][3];    // packed (wr0, wr1)
    h2    Fw23[3][3];    // packed (wr2, wr3)
    int   Fm[3][3];      // span index m (clamped to [0,10])

    auto loadrow = [&](int y, int set) {
        float vC = 0.f, vL = 0.f, vR = 0.f;
        if ((unsigned)y < (unsigned)Hh) {
            const float* row = xin + y * Ww;
            vC = row[lane];
            vL = (lane == 0)  ? 0.f : row[lane - 1];
            vR = (lane == 63) ? 0.f : row[lane + 1];
        }
        float vv[3] = {vL, vC, vR};
        #pragma unroll
        for (int c = 0; c < 3; ++c) {
            float v = vv[c];
            float s = __fdividef(v, 1.f + __expf(-v));          // silu
            float u  = (v + 2.2f) * 2.5f;
            float mf = floorf(u);
            float t  = u - mf;
            int   m  = (int)mf;
            bool  inr = (m >= 0) && (m <= 10);
            m = min(max(m, 0), 10);
            float t2 = t * t, t3 = t2 * t, omt = 1.f - t;
            const float c6 = 1.f / 6.f;
            float w0 = c6 * omt * omt * omt;
            float w1 = c6 * (3.f * t3 - 6.f * t2 + 4.f);
            float w2 = c6 * (-3.f * t3 + 3.f * t2 + 3.f * t + 1.f);
            float w3 = c6 * t3;
            if (!inr) { w0 = 0.f; w1 = 0.f; w2 = 0.f; w3 = 0.f; }
            Fs[set][c]   = s;
            Fw01[set][c] = __builtin_amdgcn_cvt_pkrtz(w0, w1);
            Fw23[set][c] = __builtin_amdgcn_cvt_pkrtz(w2, w3);
            Fm[set][c]   = m;
        }
    };

    loadrow(r0 - 1, 0);
    loadrow(r0,     1);

    #pragma unroll
    for (int rr = 0; rr < 4; ++rr) {
        loadrow(r0 + rr + 1, (rr + 2) % 3);

        float acc[8];
        #pragma unroll
        for (int n = 0; n < 8; ++n) acc[n] = 0.f;

        // ---- spline path: 9 taps, 4 ds_read_b128 + 16 fdot2 each ----
        #pragma unroll
        for (int ir = 0; ir < 3; ++ir) {
            const int set = (rr + ir) % 3;
            #pragma unroll
            for (int c = 0; c < 3; ++c) {
                const int i = ir * 3 + c;
                const int m = Fm[set][c];
                const float4* rp = (const float4*)&Pl[i][m][0];
                float4 q0 = rp[0];   // pair-row m,   n=0..3
                float4 q1 = rp[1];   // pair-row m,   n=4..7
                float4 q2 = rp[4];   // pair-row m+2, n=0..3
                float4 q3 = rp[5];   // pair-row m+2, n=4..7
                float qa[8]  = {q0.x, q0.y, q0.z, q0.w, q1.x, q1.y, q1.z, q1.w};
                float qb[8]  = {q2.x, q2.y, q2.z, q2.w, q3.x, q3.y, q3.z, q3.w};
                const h2 w01 = Fw01[set][c];
                const h2 w23 = Fw23[set][c];
                #pragma unroll
                for (int n = 0; n < 8; ++n) {
                    acc[n] = __builtin_amdgcn_fdot2(w01, f2h2(qa[n]), acc[n], false);
                    acc[n] = __builtin_amdgcn_fdot2(w23, f2h2(qb[n]), acc[n], false);
                }
            }
        }

        // ---- base path: silu pairs via fdot2 against hoisted weights ----
        {
            float s9[9];
            #pragma unroll
            for (int i = 0; i < 9; ++i) s9[i] = Fs[(rr + i / 3) % 3][i % 3];
            #pragma unroll
            for (int p = 0; p < 4; ++p) {
                h2 sp = __builtin_amdgcn_cvt_pkrtz(s9[2 * p], s9[2 * p + 1]);
                #pragma unroll
                for (int n = 0; n < 8; ++n)
                    acc[n] = __builtin_amdgcn_fdot2(sp, hbp[p][n], acc[n], false);
            }
            #pragma unroll
            for (int n = 0; n < 8; ++n)
                acc[n] += s9[8] * hb8[n];
        }

        #pragma unroll
        for (int n = 0; n < 8; ++n)
            op[n * (Hh * Ww) + rr * Ww] = acc[n];
    }
}

extern "C" void kernel_launch(void* const* d_in, const int* in_sizes, int n_in,
                              void* d_out, int out_size, void* d_ws, size_t ws_size,
                              hipStream_t stream) {
    const float* x  = (const float*)d_in[0];
    const float* bw = (const float*)d_in[1];
    const float* sw = (const float*)d_in[2];
    const float* ss = (const float*)d_in[3];
    float* out = (float*)d_out;

    dim3 block(256, 1, 1);
    dim3 grid(1024, 1, 1);   // 256 bc * 4 strip-groups; wave = 4-row strip
    hipLaunchKernelGGL(kan_conv_kernel, grid, block, 0, stream, x, bw, sw, ss, out);
}